// Round 1
// 983.295 us; speedup vs baseline: 1.0106x; 1.0106x over previous
//
#include <hip/hip_runtime.h>
#include <cmath>

// GNN fused kernel: B=1e6 nodes, C=3 channels, K=64 neighbors.
//   h[c]   = tanh(Ws[c,:]·x + bs[c])
//   pooled = mean_k neighbors[:, k]
//   z[o]   = sum_c Wc[o,c,0]*h[c] + Wc[o,c,1]*pooled[c] + bc[o]
//   out    = tanh(tanh(z))
//
// Memory-bound: neighbors = 768 MB read-once dominates. Layout (B,C,K) means
// each node owns 192 contiguous floats = 48 float4s. Each (node,channel) =
// 16 consecutive float4s = one 16-lane shuffle-reduce group (16 | 64, never
// straddles a wave).
//
// v2 change vs 988µs baseline: baseline used 250k blocks of 192 threads with
// ONE float4 load per thread -> MLP=1 per thread, block lifetime = one HBM
// round-trip + barrier, latency-bound at ~1.6 TB/s. Now each block processes
// 128 nodes via a 32-iteration loop of independent loads (ILP ~4-8 in
// flight), a SINGLE __syncthreads, x staged in LDS overlapping the neighbor
// stream, and a fully coalesced 384-float epilogue store. Grid = 7813 blocks.

#define THREADS 192
#define NITER   32
#define NPB     (4 * NITER)   // nodes per block = 128

__global__ __launch_bounds__(THREADS) void gnn_fused_kernel(
    const float* __restrict__ x,       // [B,3,1]
    const float4* __restrict__ nbr,    // [B,3,64] viewed as float4
    const float* __restrict__ Ws,      // [3,3]
    const float* __restrict__ bs,      // [3]
    const float* __restrict__ Wc,      // [3,3,2]
    const float* __restrict__ bc,      // [3]
    float* __restrict__ out,           // [B,3,1]
    long long num_nodes)
{
    __shared__ float pooled[NPB * 3];  // [local_node][channel]
    __shared__ float xs[NPB * 3];      // staged x for this block's nodes

    const int t = threadIdx.x;
    const long long node_base = (long long)blockIdx.x * NPB;
    const long long f4_base   = node_base * 48;
    const long long total_f4  = num_nodes * 48;
    const long long total_xf  = num_nodes * 3;

    // Stage x for the block's 128 nodes (384 floats, coalesced); these loads
    // are issued before the neighbor loop so they overlap the big stream.
#pragma unroll
    for (int j = t; j < NPB * 3; j += THREADS) {
        const long long gx = node_base * 3 + j;
        xs[j] = (gx < total_xf) ? x[gx] : 0.0f;
    }

    // Neighbor stream: 32 iterations x 192 threads x 16B, all loads
    // independent across iterations. Per iteration the block covers
    // 192 consecutive float4s = 4 nodes; group g = t>>4 maps to
    // local node it*4 + g/3, channel g%3. Lane-0-of-16 writes pooled.
#pragma unroll 4
    for (int it = 0; it < NITER; ++it) {
        const long long gf = f4_base + (long long)(it * THREADS + t);
        float s = 0.0f;
        if (gf < total_f4) {
            const float4 v = nbr[gf];
            s = (v.x + v.y) + (v.z + v.w);
        }
        s += __shfl_xor(s, 1);
        s += __shfl_xor(s, 2);
        s += __shfl_xor(s, 4);
        s += __shfl_xor(s, 8);
        if ((t & 15) == 0) pooled[it * 12 + (t >> 4)] = s * (1.0f / 64.0f);
    }
    __syncthreads();   // the ONLY barrier in the kernel

    // Epilogue: 384 outputs per block, 2 per thread, coalesced stores.
#pragma unroll
    for (int j = t; j < NPB * 3; j += THREADS) {
        const int n = j / 3;           // local node
        const int o = j - n * 3;       // output channel
        const long long node = node_base + n;
        if (node < num_nodes) {
            const float x0 = xs[n * 3 + 0];
            const float x1 = xs[n * 3 + 1];
            const float x2 = xs[n * 3 + 2];
            float z = bc[o];
#pragma unroll
            for (int c = 0; c < 3; ++c) {
                const float h = tanhf(Ws[c * 3 + 0] * x0 + Ws[c * 3 + 1] * x1 +
                                      Ws[c * 3 + 2] * x2 + bs[c]);
                z += Wc[o * 6 + c * 2 + 0] * h +
                     Wc[o * 6 + c * 2 + 1] * pooled[n * 3 + c];
            }
            out[node * 3 + o] = tanhf(tanhf(z));
        }
    }
}

extern "C" void kernel_launch(void* const* d_in, const int* in_sizes, int n_in,
                              void* d_out, int out_size, void* d_ws, size_t ws_size,
                              hipStream_t stream) {
    const float*  x   = (const float*)d_in[0];
    const float4* nbr = (const float4*)d_in[1];
    const float*  Ws  = (const float*)d_in[2];
    const float*  bs  = (const float*)d_in[3];
    const float*  Wc  = (const float*)d_in[4];
    const float*  bc  = (const float*)d_in[5];
    float* out = (float*)d_out;

    const long long num_nodes = (long long)in_sizes[0] / 3;  // x is [B,3,1]
    const long long blocks = (num_nodes + NPB - 1) / NPB;

    gnn_fused_kernel<<<(unsigned)blocks, THREADS, 0, stream>>>(
        x, nbr, Ws, bs, Wc, bc, out, num_nodes);
}